// Round 6
// baseline (298.865 us; speedup 1.0000x reference)
//
#include <hip/hip_runtime.h>
#include <hip/hip_bf16.h>
#include <cstdint>
#include <cstddef>

// Problem constants (shapes fixed by the reference)
#define NN      10000      // nodes (M == N == 10000)
#define DD      256        // feature dim
#define KSTEP64 157        // ceil(10016/64) K-steps of 64
#define MB2     79         // ceil(10000/128) m-blocks for big GEMM (BM=128)
#define KSPLIT  6          // 79*6 = 474 blocks, ~2/CU

typedef __bf16 bf16x8 __attribute__((ext_vector_type(8)));
typedef float  f32x4  __attribute__((ext_vector_type(4)));

// ---- workspace layout (bytes) ----
#define XG_OFF   0ull
#define XG_SIZE  (32ull * 10000 * 16)        // [q=kb*4+g][row] 16B chunks (bf16 X, MFMA-A layout)
#define WG_OFF   (XG_OFF + XG_SIZE)
#define WG_SIZE  (32ull * 256 * 16)          // [q][n] chunks (bf16 W, MFMA-B layout)
#define INP_OFF  (WG_OFF + WG_SIZE)
#define INP_SIZE (10000ull * 256 * 4)        // inp = X@W, f32
#define E_OFF    (INP_OFF + INP_SIZE)
#define E_SIZE   (10016ull * 4)
#define HS_OFF   (E_OFF + E_SIZE)
#define HS_SIZE  (10016ull * 4)
#define G_OFF    (HS_OFF + HS_SIZE)
#define G_SIZE   (10016ull * 4)
#define YG_OFF   (G_OFF + G_SIZE + 256ull)   // keep 256B alignment
#define YG_SIZE  (318ull * 1088 * 16)        // [kb32][chunk]; kb 313..317 zero pads
#define PN_OFF   (YG_OFF + YG_SIZE)
#define PN_SIZE  ((size_t)KSPLIT * 10000 * 272 * 4)  // per-kc partials
#define BITS_OFF (PN_OFF + PN_SIZE)
#define BITS_SIZE (10000ull * 1280)          // 1-bit adj: [row][160 u64], row stride 1280B

// async global(16B) -> LDS copy; dest = wave-uniform base + lane*16
__device__ __forceinline__ void gl_lds16(const void* g, void* lds) {
    __builtin_amdgcn_global_load_lds(
        (const __attribute__((address_space(1))) unsigned int*)g,
        (__attribute__((address_space(3))) unsigned int*)lds,
        16, 0, 0);
}

// ---------------- K-1: pack adj int32 -> 1 bit (pure streaming, ~HBM roofline) ----------------
// block = one row; thread byte b covers k = b*8..b*8+7 (LSB-first); bytes >=1250 are 0.
__global__ __launch_bounds__(256) void k_pack(const int* __restrict__ adj,
                                              unsigned char* __restrict__ bits) {
    int row = blockIdx.x;
    const int* src = adj + (size_t)row * 10000;
    unsigned char* brow = bits + (size_t)row * 1280;
#pragma unroll
    for (int it = 0; it < 5; ++it) {
        int b = it * 256 + threadIdx.x;   // 0..1279
        unsigned int byte = 0;
        int k0 = b * 8;
        if (k0 + 8 <= 10000) {
            const int4* p = (const int4*)(src + k0);
            int4 u0 = p[0], u1 = p[1];
            byte = (unsigned)(u0.x > 0)        | ((unsigned)(u0.y > 0) << 1)
                 | ((unsigned)(u0.z > 0) << 2) | ((unsigned)(u0.w > 0) << 3)
                 | ((unsigned)(u1.x > 0) << 4) | ((unsigned)(u1.y > 0) << 5)
                 | ((unsigned)(u1.z > 0) << 6) | ((unsigned)(u1.w > 0) << 7);
        }
        brow[b] = (unsigned char)byte;
    }
}

// ---------------- K0a: build XG (bf16 X in MFMA-A chunk layout) ----------------
__global__ __launch_bounds__(256) void k_build_xg(const float* __restrict__ X,
                                                  bf16x8* __restrict__ XG) {
    int idx = blockIdx.x * 256 + threadIdx.x;   // 0..319999
    int row = idx >> 5;
    int q   = idx & 31;
    const float* src = X + row * 256 + q * 8;
    bf16x8 v;
#pragma unroll
    for (int j = 0; j < 8; ++j) v[j] = (__bf16)src[j];
    XG[q * 10000 + row] = v;
}

// ---------------- K0b: build WG (bf16 W in MFMA-B chunk layout) ----------------
__global__ __launch_bounds__(256) void k_build_wg(const float* __restrict__ W,
                                                  bf16x8* __restrict__ WG) {
    int e = blockIdx.x * 256 + threadIdx.x;     // 0..8191
    int q = e >> 8;
    int n = e & 255;
    bf16x8 v;
#pragma unroll
    for (int j = 0; j < 8; ++j) v[j] = (__bf16)W[(q * 8 + j) * 256 + n];
    WG[e] = v;
}

// ---------------- K1: inp = X@W (MFMA), fused tanh/e/hsum (LDS cross-wave reduce) ----------------
__global__ __launch_bounds__(256) void k_gemm1(const bf16x8* __restrict__ XG,
                                               const bf16x8* __restrict__ WG,
                                               const float* __restrict__ bvec,
                                               const float* __restrict__ avec,
                                               float* __restrict__ inp,
                                               float* __restrict__ evec,
                                               float* __restrict__ hsumv) {
    __shared__ bf16x8 Ash[320];    // (g*80 + r)
    __shared__ bf16x8 Bsh[1024];   // (g*256 + n)
    __shared__ float ePart[4][80];
    __shared__ float hPart[4][80];
    int tid = threadIdx.x, wid = tid >> 6, lane = tid & 63;
    int l15 = lane & 15, l4 = lane >> 4;
    int mb = blockIdx.x;

    f32x4 acc[4][5];
#pragma unroll
    for (int c = 0; c < 4; ++c)
#pragma unroll
        for (int rt = 0; rt < 5; ++rt) acc[c][rt] = f32x4{0.f, 0.f, 0.f, 0.f};

    for (int kb = 0; kb < 8; ++kb) {
        for (int rr = wid; rr < 5; rr += 4) {
            int c = rr * 64 + lane;
            int g = c / 80, r = c - g * 80;
            gl_lds16(XG + ((kb * 4 + g) * 10000 + mb * 80 + r), (char*)Ash + rr * 1024);
        }
        for (int rr = wid; rr < 16; rr += 4)
            gl_lds16(WG + kb * 1024 + rr * 64 + lane, (char*)Bsh + rr * 1024);
        __syncthreads();

        bf16x8 af[5];
#pragma unroll
        for (int rt = 0; rt < 5; ++rt) af[rt] = Ash[l4 * 80 + rt * 16 + l15];
#pragma unroll
        for (int c = 0; c < 4; ++c) {
            bf16x8 bf = Bsh[l4 * 256 + (wid * 4 + c) * 16 + l15];
#pragma unroll
            for (int rt = 0; rt < 5; ++rt)
                acc[c][rt] = __builtin_amdgcn_mfma_f32_16x16x32_bf16(af[rt], bf, acc[c][rt], 0, 0, 0);
        }
        __syncthreads();
    }

    float pe[5][4], ph[5][4];
#pragma unroll
    for (int rt = 0; rt < 5; ++rt)
#pragma unroll
        for (int rg = 0; rg < 4; ++rg) { pe[rt][rg] = 0.f; ph[rt][rg] = 0.f; }

#pragma unroll
    for (int c = 0; c < 4; ++c) {
        int col = (wid * 4 + c) * 16 + l15;
        float av = avec[col];
        float bv = bvec[col];
#pragma unroll
        for (int rt = 0; rt < 5; ++rt) {
#pragma unroll
            for (int rg = 0; rg < 4; ++rg) {
                int row = mb * 80 + rt * 16 + l4 * 4 + rg;
                float v = acc[c][rt][rg];            // inp excludes bias (per reference)
                inp[row * 256 + col] = v;
                float h = tanhf(v + bv);
                pe[rt][rg] += h * av;
                ph[rt][rg] += h;
            }
        }
    }
#pragma unroll
    for (int rt = 0; rt < 5; ++rt) {
#pragma unroll
        for (int rg = 0; rg < 4; ++rg) {
            float se = pe[rt][rg], sh = ph[rt][rg];
#pragma unroll
            for (int m = 1; m < 16; m <<= 1) {
                se += __shfl_xor(se, m);
                sh += __shfl_xor(sh, m);
            }
            if (l15 == 0) {
                int lr = rt * 16 + l4 * 4 + rg;   // 0..79
                ePart[wid][lr] = se;
                hPart[wid][lr] = sh;
            }
        }
    }
    __syncthreads();
    if (tid < 80) {
        float e = ePart[0][tid] + ePart[1][tid] + ePart[2][tid] + ePart[3][tid];
        float h = hPart[0][tid] + hPart[1][tid] + hPart[2][tid] + hPart[3][tid];
        evec[mb * 80 + tid] = e;
        hsumv[mb * 80 + tid] = h;
    }
}

// ---------------- K2: global max of e over valid nodes, then g = exp(e-gmax) ----------------
__global__ __launch_bounds__(1024) void k_softmax_g(const float* __restrict__ evec,
                                                    const float* __restrict__ hsumv,
                                                    float* __restrict__ gv) {
    __shared__ float red[1024];
    int tid = threadIdx.x;
    float m = -3.0e38f;
    for (int i = tid; i < NN; i += 1024)
        if (hsumv[i] != 0.0f) m = fmaxf(m, evec[i]);
    red[tid] = m;
    __syncthreads();
    for (int s = 512; s > 0; s >>= 1) {
        if (tid < s) red[tid] = fmaxf(red[tid], red[tid + s]);
        __syncthreads();
    }
    float gmax = red[0];
    if (gmax < -1.0e37f) gmax = 0.0f;
    for (int i = tid; i < 10016; i += 1024) {
        float g = 0.0f;
        if (i < NN && hsumv[i] != 0.0f) g = expf(evec[i] - gmax);
        gv[i] = g;
    }
}

// ---------------- K3: build YG = pre-chunked bf16 B tiles for the big GEMM ----------------
// grid 318: kb >= 313 hits the k<NN guard everywhere -> zero pads
__global__ __launch_bounds__(256) void k_build_yg(const float* __restrict__ inp,
                                                  const float* __restrict__ gv,
                                                  bf16x8* __restrict__ YG) {
    int kb = blockIdx.x;   // 0..317
    for (int c = threadIdx.x; c < 1088; c += 256) {
        int gq = c / 272, n = c - gq * 272;
        int k0 = kb * 32 + gq * 8;
        bf16x8 v;
#pragma unroll
        for (int j = 0; j < 8; ++j) {
            int k = k0 + j;
            float val = 0.0f;
            if (k < NN) {
                float gk = gv[k];
                if (n < 256) val = gk * inp[k * 256 + n];
                else if (n == 256) val = gk;
            }
            v[j] = (__bf16)val;
        }
        YG[kb * 1088 + c] = v;
    }
}

// ---- 8 bits (LSB-first) -> bf16x8 {0,1} fragment ----
__device__ __forceinline__ bf16x8 expand_byte(unsigned int b) {
    union { bf16x8 v; unsigned int u[4]; } r;
    r.u[0] = ((b & 1u)   ? 0x3F80u : 0u) | ((b & 2u)   ? 0x3F800000u : 0u);
    r.u[1] = ((b & 4u)   ? 0x3F80u : 0u) | ((b & 8u)   ? 0x3F800000u : 0u);
    r.u[2] = ((b & 16u)  ? 0x3F80u : 0u) | ((b & 32u)  ? 0x3F800000u : 0u);
    r.u[3] = ((b & 64u)  ? 0x3F80u : 0u) | ((b & 128u) ? 0x3F800000u : 0u);
    return r.v;
}

// ---------------- K4: num_kc = adjbits @ Y ----------------
// BM=128, 4 waves = 2 rowG x 2 colG; per wave: 64 rows (4 row-tiles) x ~136 cols
// (colG0: ct 0..8, colG1: ct 9..16). A: 4 u64/lane/step from 12.8MB bitmask
// (L2/L3-resident), expanded in-register. B: LDS dbuf + counted vmcnt(4),
// 1-step prefetch (round-3 proven pattern). Bijective kc-major XCD swizzle.
__global__ __launch_bounds__(256, 2) void k_attn_gemm(const unsigned char* __restrict__ bits,
                                                      const bf16x8* __restrict__ YG,
                                                      float* __restrict__ pnum) {
    __shared__ bf16x8 Bsh[2][2176];   // double-buffered 64x272 bf16 tiles (69632 B)
    int tid = threadIdx.x, wid = tid >> 6, lane = tid & 63;
    int l15 = lane & 15, l4 = lane >> 4;
    int rowG = wid >> 1, colG = wid & 1;
    int ctBase = colG * 9;
    int nct = 9 - colG;                // 9 or 8 col-tiles

    // bijective XCD swizzle (m204): 474 = 8*59 + 2
    int orig = blockIdx.x;
    const int nwg = MB2 * KSPLIT, q = nwg >> 3, r = nwg & 7;
    int x = orig & 7, o = orig >> 3;
    int logical = (x < r ? x * (q + 1) : r * (q + 1) + (x - r) * q) + o;
    int kc = logical / MB2, mb = logical % MB2;   // kc-major: <=2 kc slices per XCD
    int s0 = (kc * KSTEP64) / KSPLIT, s1 = ((kc + 1) * KSTEP64) / KSPLIT;

    int r0w = mb * 128 + rowG * 64;
    const unsigned char* rowPtr[4];
#pragma unroll
    for (int rt = 0; rt < 4; ++rt)
        rowPtr[rt] = bits + (size_t)min(r0w + rt * 16 + l15, NN - 1) * 1280;

    f32x4 acc[4][9];
#pragma unroll
    for (int rt = 0; rt < 4; ++rt)
#pragma unroll
        for (int ct = 0; ct < 9; ++ct) acc[rt][ct] = f32x4{0.f, 0.f, 0.f, 0.f};

    unsigned long long aC[4], aN[4];

    auto stageB = [&](int sTile, int bufIdx) {
        const bf16x8* src = YG + (size_t)sTile * 2176;
        char* dst = (char*)&Bsh[bufIdx][0];
#pragma unroll
        for (int i = 0; i < 9; ++i) {
            int rr = wid + i * 4;
            if (rr < 34) gl_lds16(src + rr * 64 + lane, dst + rr * 1024);
        }
    };
    auto loadA = [&](int sTile, unsigned long long* dst) {
#pragma unroll
        for (int rt = 0; rt < 4; ++rt)
            dst[rt] = *(const unsigned long long*)(rowPtr[rt] + sTile * 8);
    };
    auto compute = [&](const unsigned long long* aBits, int bufIdx) {
#pragma unroll
        for (int h = 0; h < 2; ++h) {
            bf16x8 fa[4];
#pragma unroll
            for (int rt = 0; rt < 4; ++rt)
                fa[rt] = expand_byte((unsigned int)(aBits[rt] >> (h * 32 + (l4 << 3))) & 0xFFu);
#pragma unroll
            for (int ct = 0; ct < 9; ++ct) {
                if (colG == 1 && ct == 8) break;
                bf16x8 fb = Bsh[bufIdx][h * 1088 + l4 * 272 + (ctBase + ct) * 16 + l15];
#pragma unroll
                for (int rt = 0; rt < 4; ++rt)
                    acc[rt][ct] = __builtin_amdgcn_mfma_f32_16x16x32_bf16(fa[rt], fb, acc[rt][ct], 0, 0, 0);
            }
        }
    };

    // ---- prologue ----
    stageB(s0, 0);
    __builtin_amdgcn_sched_barrier(0);
    loadA(s0, aC);
    asm volatile("s_waitcnt vmcnt(4)" ::: "memory");   // own B(s0) drained; A(s0) in flight
    __builtin_amdgcn_s_barrier();

    // ---- main loop: 1-step prefetch, counted vmcnt (never 0) ----
    int buf = 0;
    for (int s = s0; s < s1 - 1; ++s) {
        stageB(s + 1, buf ^ 1);
        __builtin_amdgcn_sched_barrier(0);
        loadA(s + 1, aN);
        __builtin_amdgcn_sched_barrier(0);
        compute(aC, buf);
        asm volatile("s_waitcnt vmcnt(4)" ::: "memory");   // drain own B(s+1); keep A(s+1)
        __builtin_amdgcn_s_barrier();
        buf ^= 1;
#pragma unroll
        for (int rt = 0; rt < 4; ++rt) aC[rt] = aN[rt];
    }
    compute(aC, buf);   // last step: no prefetch

    // ---- epilogue: plain stores to per-kc partial buffer ----
    float* base = pnum + (size_t)kc * 10000 * 272;
#pragma unroll
    for (int rt = 0; rt < 4; ++rt) {
#pragma unroll
        for (int ct = 0; ct < 9; ++ct) {
            if (colG == 1 && ct == 8) break;
            int col = (ctBase + ct) * 16 + l15;
#pragma unroll
            for (int rg = 0; rg < 4; ++rg) {
                int row = r0w + rt * 16 + l4 * 4 + rg;
                if (row < NN) base[(size_t)row * 272 + col] = acc[rt][ct][rg];
            }
        }
    }
}

// ---------------- K5: out = (sum_kc num_kc) / max(sum_kc den_kc, 1e-30) ----------------
__global__ __launch_bounds__(256) void k_finalize(const float* __restrict__ pnum,
                                                  float* __restrict__ out) {
    int idx = blockIdx.x * 256 + threadIdx.x;   // 0..639999 (float4 units)
    int i = idx >> 6, q = idx & 63;
    float4 sv = {0.f, 0.f, 0.f, 0.f};
    float den = 0.f;
#pragma unroll
    for (int kc = 0; kc < KSPLIT; ++kc) {
        const float* row = pnum + ((size_t)kc * 10000 + i) * 272;
        float4 v = ((const float4*)row)[q];
        sv.x += v.x; sv.y += v.y; sv.z += v.z; sv.w += v.w;
        den += row[256];
    }
    float r = 1.0f / fmaxf(den, 1e-30f);
    float4 o;
    o.x = sv.x * r; o.y = sv.y * r; o.z = sv.z * r; o.w = sv.w * r;
    ((float4*)(out + (size_t)i * 256))[q] = o;
}

extern "C" void kernel_launch(void* const* d_in, const int* in_sizes, int n_in,
                              void* d_out, int out_size, void* d_ws, size_t ws_size,
                              hipStream_t stream) {
    const float* X    = (const float*)d_in[0];
    const int*   adj  = (const int*)d_in[1];
    const float* W    = (const float*)d_in[3];
    const float* bvec = (const float*)d_in[4];
    const float* avec = (const float*)d_in[5];
    float* out = (float*)d_out;

    char* ws = (char*)d_ws;
    bf16x8* XG   = (bf16x8*)(ws + XG_OFF);
    bf16x8* WG   = (bf16x8*)(ws + WG_OFF);
    float*  inp  = (float*)(ws + INP_OFF);
    float*  evec = (float*)(ws + E_OFF);
    float*  hsv  = (float*)(ws + HS_OFF);
    float*  gv   = (float*)(ws + G_OFF);
    bf16x8* YG   = (bf16x8*)(ws + YG_OFF);
    float*  pnum = (float*)(ws + PN_OFF);
    unsigned char* bits = (unsigned char*)(ws + BITS_OFF);

    k_pack<<<NN, 256, 0, stream>>>(adj, bits);
    k_build_xg<<<1250, 256, 0, stream>>>(X, XG);
    k_build_wg<<<32, 256, 0, stream>>>(W, WG);
    k_gemm1<<<125, 256, 0, stream>>>(XG, WG, bvec, avec, inp, evec, hsv);
    k_softmax_g<<<1, 1024, 0, stream>>>(evec, hsv, gv);
    k_build_yg<<<318, 256, 0, stream>>>(inp, gv, YG);
    k_attn_gemm<<<MB2 * KSPLIT, 256, 0, stream>>>(bits, YG, pnum);
    k_finalize<<<2500, 256, 0, stream>>>(pnum, out);
}

// Round 7
// 262.268 us; speedup vs baseline: 1.1395x; 1.1395x over previous
//
#include <hip/hip_runtime.h>
#include <hip/hip_bf16.h>
#include <cstdint>
#include <cstddef>

// Problem constants (shapes fixed by the reference)
#define NN      10000      // nodes (M == N == 10000)
#define DD      256        // feature dim
#define KSTEPS  313        // ceil(10016/32) K-steps of 32
#define MB64    157        // ceil(10000/64) m-blocks for big GEMM (BM=64)
#define KSPLIT  5          // 157*5 = 785 blocks ~= 3.07/CU at 3 blocks/CU occupancy

typedef __bf16 bf16x8 __attribute__((ext_vector_type(8)));
typedef float  f32x4  __attribute__((ext_vector_type(4)));

// ---- workspace layout (bytes) ----
#define XG_OFF   0ull
#define XG_SIZE  (32ull * 10000 * 16)        // [q=kb*4+g][row] 16B chunks (bf16 X, MFMA-A layout)
#define WG_OFF   (XG_OFF + XG_SIZE)
#define WG_SIZE  (32ull * 256 * 16)          // [q][n] chunks (bf16 W, MFMA-B layout)
#define INP_OFF  (WG_OFF + WG_SIZE)
#define INP_SIZE (10000ull * 256 * 4)        // inp = X@W, f32
#define E_OFF    (INP_OFF + INP_SIZE)
#define E_SIZE   (10016ull * 4)
#define HS_OFF   (E_OFF + E_SIZE)
#define HS_SIZE  (10016ull * 4)
#define G_OFF    (HS_OFF + HS_SIZE)
#define G_SIZE   (10016ull * 4)
#define YG_OFF   (G_OFF + G_SIZE + 256ull)   // keep 256B alignment
#define YG_SIZE  (318ull * 1088 * 16)        // [kb32][chunk]; kb 313..317 zero pads
#define PN_OFF   (YG_OFF + YG_SIZE)
#define PN_SIZE  ((size_t)KSPLIT * 10000 * 272 * 4)  // per-kc partials: 256 numer cols + den at col 256

// async global(16B) -> LDS copy; dest = wave-uniform base + lane*16
__device__ __forceinline__ void gl_lds16(const void* g, void* lds) {
    __builtin_amdgcn_global_load_lds(
        (const __attribute__((address_space(1))) unsigned int*)g,
        (__attribute__((address_space(3))) unsigned int*)lds,
        16, 0, 0);
}

// ---------------- K0a: build XG (bf16 X in MFMA-A chunk layout) ----------------
__global__ __launch_bounds__(256) void k_build_xg(const float* __restrict__ X,
                                                  bf16x8* __restrict__ XG) {
    int idx = blockIdx.x * 256 + threadIdx.x;   // 0..319999
    int row = idx >> 5;
    int q   = idx & 31;
    const float* src = X + row * 256 + q * 8;
    bf16x8 v;
#pragma unroll
    for (int j = 0; j < 8; ++j) v[j] = (__bf16)src[j];
    XG[q * 10000 + row] = v;
}

// ---------------- K0b: build WG (bf16 W in MFMA-B chunk layout) ----------------
__global__ __launch_bounds__(256) void k_build_wg(const float* __restrict__ W,
                                                  bf16x8* __restrict__ WG) {
    int e = blockIdx.x * 256 + threadIdx.x;     // 0..8191
    int q = e >> 8;
    int n = e & 255;
    bf16x8 v;
#pragma unroll
    for (int j = 0; j < 8; ++j) v[j] = (__bf16)W[(q * 8 + j) * 256 + n];
    WG[e] = v;
}

// ---------------- K1: inp = X@W (MFMA), fused tanh/e/hsum (LDS cross-wave reduce) ----------------
__global__ __launch_bounds__(256) void k_gemm1(const bf16x8* __restrict__ XG,
                                               const bf16x8* __restrict__ WG,
                                               const float* __restrict__ bvec,
                                               const float* __restrict__ avec,
                                               float* __restrict__ inp,
                                               float* __restrict__ evec,
                                               float* __restrict__ hsumv) {
    __shared__ bf16x8 Ash[320];    // (g*80 + r)
    __shared__ bf16x8 Bsh[1024];   // (g*256 + n)
    __shared__ float ePart[4][80];
    __shared__ float hPart[4][80];
    int tid = threadIdx.x, wid = tid >> 6, lane = tid & 63;
    int l15 = lane & 15, l4 = lane >> 4;
    int mb = blockIdx.x;

    f32x4 acc[4][5];
#pragma unroll
    for (int c = 0; c < 4; ++c)
#pragma unroll
        for (int rt = 0; rt < 5; ++rt) acc[c][rt] = f32x4{0.f, 0.f, 0.f, 0.f};

    for (int kb = 0; kb < 8; ++kb) {
        for (int rr = wid; rr < 5; rr += 4) {
            int c = rr * 64 + lane;
            int g = c / 80, r = c - g * 80;
            gl_lds16(XG + ((kb * 4 + g) * 10000 + mb * 80 + r), (char*)Ash + rr * 1024);
        }
        for (int rr = wid; rr < 16; rr += 4)
            gl_lds16(WG + kb * 1024 + rr * 64 + lane, (char*)Bsh + rr * 1024);
        __syncthreads();

        bf16x8 af[5];
#pragma unroll
        for (int rt = 0; rt < 5; ++rt) af[rt] = Ash[l4 * 80 + rt * 16 + l15];
#pragma unroll
        for (int c = 0; c < 4; ++c) {
            bf16x8 bf = Bsh[l4 * 256 + (wid * 4 + c) * 16 + l15];
#pragma unroll
            for (int rt = 0; rt < 5; ++rt)
                acc[c][rt] = __builtin_amdgcn_mfma_f32_16x16x32_bf16(af[rt], bf, acc[c][rt], 0, 0, 0);
        }
        __syncthreads();
    }

    float pe[5][4], ph[5][4];
#pragma unroll
    for (int rt = 0; rt < 5; ++rt)
#pragma unroll
        for (int rg = 0; rg < 4; ++rg) { pe[rt][rg] = 0.f; ph[rt][rg] = 0.f; }

#pragma unroll
    for (int c = 0; c < 4; ++c) {
        int col = (wid * 4 + c) * 16 + l15;
        float av = avec[col];
        float bv = bvec[col];
#pragma unroll
        for (int rt = 0; rt < 5; ++rt) {
#pragma unroll
            for (int rg = 0; rg < 4; ++rg) {
                int row = mb * 80 + rt * 16 + l4 * 4 + rg;
                float v = acc[c][rt][rg];            // inp excludes bias (per reference)
                inp[row * 256 + col] = v;
                float h = tanhf(v + bv);
                pe[rt][rg] += h * av;
                ph[rt][rg] += h;
            }
        }
    }
#pragma unroll
    for (int rt = 0; rt < 5; ++rt) {
#pragma unroll
        for (int rg = 0; rg < 4; ++rg) {
            float se = pe[rt][rg], sh = ph[rt][rg];
#pragma unroll
            for (int m = 1; m < 16; m <<= 1) {
                se += __shfl_xor(se, m);
                sh += __shfl_xor(sh, m);
            }
            if (l15 == 0) {
                int lr = rt * 16 + l4 * 4 + rg;   // 0..79
                ePart[wid][lr] = se;
                hPart[wid][lr] = sh;
            }
        }
    }
    __syncthreads();
    if (tid < 80) {
        float e = ePart[0][tid] + ePart[1][tid] + ePart[2][tid] + ePart[3][tid];
        float h = hPart[0][tid] + hPart[1][tid] + hPart[2][tid] + hPart[3][tid];
        evec[mb * 80 + tid] = e;
        hsumv[mb * 80 + tid] = h;
    }
}

// ---------------- K2: global max of e over valid nodes, then g = exp(e-gmax) ----------------
__global__ __launch_bounds__(1024) void k_softmax_g(const float* __restrict__ evec,
                                                    const float* __restrict__ hsumv,
                                                    float* __restrict__ gv) {
    __shared__ float red[1024];
    int tid = threadIdx.x;
    float m = -3.0e38f;
    for (int i = tid; i < NN; i += 1024)
        if (hsumv[i] != 0.0f) m = fmaxf(m, evec[i]);
    red[tid] = m;
    __syncthreads();
    for (int s = 512; s > 0; s >>= 1) {
        if (tid < s) red[tid] = fmaxf(red[tid], red[tid + s]);
        __syncthreads();
    }
    float gmax = red[0];
    if (gmax < -1.0e37f) gmax = 0.0f;
    for (int i = tid; i < 10016; i += 1024) {
        float g = 0.0f;
        if (i < NN && hsumv[i] != 0.0f) g = expf(evec[i] - gmax);
        gv[i] = g;
    }
}

// ---------------- K3: build YG = pre-chunked bf16 B tiles for the big GEMM ----------------
// grid 318: kb >= 313 hits the k<NN guard everywhere -> zero pads
__global__ __launch_bounds__(256) void k_build_yg(const float* __restrict__ inp,
                                                  const float* __restrict__ gv,
                                                  bf16x8* __restrict__ YG) {
    int kb = blockIdx.x;   // 0..317
    for (int c = threadIdx.x; c < 1088; c += 256) {
        int gq = c / 272, n = c - gq * 272;
        int k0 = kb * 32 + gq * 8;
        bf16x8 v;
#pragma unroll
        for (int j = 0; j < 8; ++j) {
            int k = k0 + j;
            float val = 0.0f;
            if (k < NN) {
                float gk = gv[k];
                if (n < 256) val = gk * inp[k * 256 + n];
                else if (n == 256) val = gk;
            }
            v[j] = (__bf16)val;
        }
        YG[kb * 1088 + c] = v;
    }
}

// ---- int32 {0,1} pair-of-int4 -> bf16x8 {0,1} fragment ----
__device__ __forceinline__ bf16x8 cvt_adj(int4 a, int4 b) {
    union { bf16x8 v; unsigned int u[4]; } r;
    r.u[0] = (a.x > 0 ? 0x3F80u : 0u) | (a.y > 0 ? 0x3F800000u : 0u);
    r.u[1] = (a.z > 0 ? 0x3F80u : 0u) | (a.w > 0 ? 0x3F800000u : 0u);
    r.u[2] = (b.x > 0 ? 0x3F80u : 0u) | (b.y > 0 ? 0x3F800000u : 0u);
    r.u[3] = (b.z > 0 ? 0x3F80u : 0u) | (b.w > 0 ? 0x3F800000u : 0u);
    return r.v;
}

// ---------------- K4: num_kc = adj @ Y  (occupancy-first redesign) ----------------
// BM=64, 4 waves = 2 rowG x 2 colG. Per wave: 32 rows (2 row-tiles) x 9 col-tiles
// (ctBase 0 or 8; tile 8 computed by both colG — identical values, benign dup store).
// acc[2][9]=72 AGPR + ~90 VGPR -> 3 waves/SIMD (12 waves/CU, 3 blocks/CU) — the
// round-3 structure was register-bound at 2 waves/SIMD and couldn't stream A at BW.
// BK=32: LDS dbuf 34.8KB. A direct from HBM, reload-in-place 1 step ahead.
// Counted vmcnt(4): own B-stage drained at barrier, A(s+1) stays in flight.
__global__ __launch_bounds__(256, 3) void k_attn_gemm(const int* __restrict__ adj,
                                                      const bf16x8* __restrict__ YG,
                                                      float* __restrict__ pnum) {
    __shared__ bf16x8 Bsh[2][1088];   // double-buffered 32x272 bf16 tiles (34816 B)
    int tid = threadIdx.x, wid = tid >> 6, lane = tid & 63;
    int l15 = lane & 15, l4 = lane >> 4;
    int rowG = wid >> 1, colG = wid & 1;
    int ctBase = colG * 8;            // colG0: ct 0..8, colG1: ct 8..16 (tile 8 shared)

    // bijective XCD swizzle (m204): 785 = 8*98 + 1; kc-major -> <=2 kc slices/XCD
    int orig = blockIdx.x;
    const int nwg = MB64 * KSPLIT, q = nwg >> 3, r = nwg & 7;
    int x = orig & 7, o = orig >> 3;
    int logical = (x < r ? x * (q + 1) : r * (q + 1) + (x - r) * q) + o;
    int kc = logical / MB64, mb = logical % MB64;
    int s0 = (kc * KSTEPS) / KSPLIT, s1 = ((kc + 1) * KSTEPS) / KSPLIT;

    // A addressing: row = l15 (+16 for row-tile 1), k-group = l4*8 (verified A-frag layout)
    int r0w = mb * 64 + rowG * 32;
    const int* pR0 = adj + (size_t)min(r0w + l15, NN - 1) * 10000;
    const int* pR1 = adj + (size_t)min(r0w + 16 + l15, NN - 1) * 10000;
    int kgrp = l4 * 8;

    f32x4 acc[2][9];
#pragma unroll
    for (int rt = 0; rt < 2; ++rt)
#pragma unroll
        for (int ct = 0; ct < 9; ++ct) acc[rt][ct] = f32x4{0.f, 0.f, 0.f, 0.f};

    int4 aA[4];   // 2 row-tiles x 2 int4 (32 K-ints) — reload-in-place

    auto stageB = [&](int sTile, int bufIdx) {
        const bf16x8* src = YG + (size_t)sTile * 1088;
        char* dst = (char*)&Bsh[bufIdx][0];
#pragma unroll
        for (int i = 0; i < 5; ++i) {
            int rr = wid + i * 4;
            if (rr < 17) gl_lds16(src + rr * 64 + lane, dst + rr * 1024);  // wid0:5, others:4
        }
    };
    auto loadA = [&](int sTile) {
        int kk = min(sTile * 32 + kgrp, 9992);   // clamp safe: B is 0 for k>=NN
        const int4* q0 = (const int4*)(pR0 + kk);
        const int4* q1 = (const int4*)(pR1 + kk);
        aA[0] = q0[0]; aA[1] = q0[1]; aA[2] = q1[0]; aA[3] = q1[1];
    };
    auto computeMFMA = [&](bf16x8 fa0, bf16x8 fa1, int bufIdx) {
#pragma unroll
        for (int ct = 0; ct < 9; ++ct) {
            bf16x8 fb = Bsh[bufIdx][l4 * 272 + (ctBase + ct) * 16 + l15];
            acc[0][ct] = __builtin_amdgcn_mfma_f32_16x16x32_bf16(fa0, fb, acc[0][ct], 0, 0, 0);
            acc[1][ct] = __builtin_amdgcn_mfma_f32_16x16x32_bf16(fa1, fb, acc[1][ct], 0, 0, 0);
        }
    };

    // ---- prologue: stage B(s0), issue A(s0) ----
    stageB(s0, 0);
    __builtin_amdgcn_sched_barrier(0);
    loadA(s0);
    asm volatile("s_waitcnt vmcnt(4)" ::: "memory");   // own B(s0) drained; A(s0) in flight
    __builtin_amdgcn_s_barrier();

    // ---- main loop: stage B(s+1); cvt A(s); reload A(s+1) in place; MFMA; counted wait ----
    int buf = 0;
    for (int s = s0; s < s1 - 1; ++s) {
        stageB(s + 1, buf ^ 1);
        __builtin_amdgcn_sched_barrier(0);
        bf16x8 fa0 = cvt_adj(aA[0], aA[1]);
        bf16x8 fa1 = cvt_adj(aA[2], aA[3]);
        loadA(s + 1);                                   // overwrites aA after cvt read
        __builtin_amdgcn_sched_barrier(0);
        computeMFMA(fa0, fa1, buf);
        asm volatile("s_waitcnt vmcnt(4)" ::: "memory");  // drain own B(s+1); keep A(s+1)
        __builtin_amdgcn_s_barrier();
        buf ^= 1;
    }
    // tail step s1-1 (B already staged + barrier'd; A in flight, compiler waits)
    {
        bf16x8 fa0 = cvt_adj(aA[0], aA[1]);
        bf16x8 fa1 = cvt_adj(aA[2], aA[3]);
        computeMFMA(fa0, fa1, buf);
    }

    // ---- epilogue: plain stores to per-kc partial buffer (dup col-tile 8 benign) ----
    float* base = pnum + (size_t)kc * 10000 * 272;
#pragma unroll
    for (int rt = 0; rt < 2; ++rt) {
#pragma unroll
        for (int ct = 0; ct < 9; ++ct) {
            int col = (ctBase + ct) * 16 + l15;
#pragma unroll
            for (int rg = 0; rg < 4; ++rg) {
                int row = r0w + rt * 16 + l4 * 4 + rg;
                if (row < NN) base[(size_t)row * 272 + col] = acc[rt][ct][rg];
            }
        }
    }
}

// ---------------- K5: out = (sum_kc num_kc) / max(sum_kc den_kc, 1e-30) ----------------
__global__ __launch_bounds__(256) void k_finalize(const float* __restrict__ pnum,
                                                  float* __restrict__ out) {
    int idx = blockIdx.x * 256 + threadIdx.x;   // 0..639999 (float4 units)
    int i = idx >> 6, q = idx & 63;
    float4 sv = {0.f, 0.f, 0.f, 0.f};
    float den = 0.f;
#pragma unroll
    for (int kc = 0; kc < KSPLIT; ++kc) {
        const float* row = pnum + ((size_t)kc * 10000 + i) * 272;
        float4 v = ((const float4*)row)[q];
        sv.x += v.x; sv.y += v.y; sv.z += v.z; sv.w += v.w;
        den += row[256];
    }
    float r = 1.0f / fmaxf(den, 1e-30f);
    float4 o;
    o.x = sv.x * r; o.y = sv.y * r; o.z = sv.z * r; o.w = sv.w * r;
    ((float4*)(out + (size_t)i * 256))[q] = o;
}

extern "C" void kernel_launch(void* const* d_in, const int* in_sizes, int n_in,
                              void* d_out, int out_size, void* d_ws, size_t ws_size,
                              hipStream_t stream) {
    const float* X    = (const float*)d_in[0];
    const int*   adj  = (const int*)d_in[1];
    const float* W    = (const float*)d_in[3];
    const float* bvec = (const float*)d_in[4];
    const float* avec = (const float*)d_in[5];
    float* out = (float*)d_out;

    char* ws = (char*)d_ws;
    bf16x8* XG   = (bf16x8*)(ws + XG_OFF);
    bf16x8* WG   = (bf16x8*)(ws + WG_OFF);
    float*  inp  = (float*)(ws + INP_OFF);
    float*  evec = (float*)(ws + E_OFF);
    float*  hsv  = (float*)(ws + HS_OFF);
    float*  gv   = (float*)(ws + G_OFF);
    bf16x8* YG   = (bf16x8*)(ws + YG_OFF);
    float*  pnum = (float*)(ws + PN_OFF);

    k_build_xg<<<1250, 256, 0, stream>>>(X, XG);
    k_build_wg<<<32, 256, 0, stream>>>(W, WG);
    k_gemm1<<<125, 256, 0, stream>>>(XG, WG, bvec, avec, inp, evec, hsv);
    k_softmax_g<<<1, 1024, 0, stream>>>(evec, hsv, gv);
    k_build_yg<<<318, 256, 0, stream>>>(inp, gv, YG);
    k_attn_gemm<<<MB64 * KSPLIT, 256, 0, stream>>>(adj, YG, pnum);
    k_finalize<<<2500, 256, 0, stream>>>(pnum, out);
}

// Round 8
// 195.296 us; speedup vs baseline: 1.5303x; 1.3429x over previous
//
#include <hip/hip_runtime.h>
#include <hip/hip_bf16.h>
#include <cstdint>
#include <cstddef>

// Problem constants (shapes fixed by the reference)
#define NN      10000      // nodes (M == N == 10000)
#define DD      256        // feature dim
#define KSTEP64 157        // ceil(10016/64) K-steps of 64
#define MB2     79         // ceil(10000/128) m-blocks for big GEMM (BM=128)
#define KSPLIT  6          // 79*6 = 474 blocks, ~2/CU

typedef __bf16 bf16x8 __attribute__((ext_vector_type(8)));
typedef float  f32x4  __attribute__((ext_vector_type(4)));

// ---- workspace layout (bytes) ----
#define XG_OFF   0ull
#define XG_SIZE  (32ull * 10000 * 16)        // [q=kb*4+g][row] 16B chunks (bf16 X, MFMA-A layout)
#define WG_OFF   (XG_OFF + XG_SIZE)
#define WG_SIZE  (32ull * 256 * 16)          // [q][n] chunks (bf16 W, MFMA-B layout)
#define INP_OFF  (WG_OFF + WG_SIZE)
#define INP_SIZE (10000ull * 256 * 4)        // inp = X@W, f32
#define E_OFF    (INP_OFF + INP_SIZE)
#define E_SIZE   (10016ull * 4)
#define HS_OFF   (E_OFF + E_SIZE)
#define HS_SIZE  (10016ull * 4)
#define G_OFF    (HS_OFF + HS_SIZE)
#define G_SIZE   (10016ull * 4)
#define YG_OFF   (G_OFF + G_SIZE + 256ull)   // keep 256B alignment
#define YG_SIZE  (318ull * 1088 * 16)        // [kb32][chunk]; kb 313..317 zero pads
#define PN_OFF   (YG_OFF + YG_SIZE)
#define PN_SIZE  ((size_t)KSPLIT * 10000 * 272 * 4)  // per-kc partials: 256 numer cols + den at col 256

// async global(16B) -> LDS copy; dest = wave-uniform base + lane*16
__device__ __forceinline__ void gl_lds16(const void* g, void* lds) {
    __builtin_amdgcn_global_load_lds(
        (const __attribute__((address_space(1))) unsigned int*)g,
        (__attribute__((address_space(3))) unsigned int*)lds,
        16, 0, 0);
}

// ---------------- K0a: build XG (bf16 X in MFMA-A chunk layout) ----------------
__global__ __launch_bounds__(256) void k_build_xg(const float* __restrict__ X,
                                                  bf16x8* __restrict__ XG) {
    int idx = blockIdx.x * 256 + threadIdx.x;   // 0..319999
    int row = idx >> 5;
    int q   = idx & 31;
    const float* src = X + row * 256 + q * 8;
    bf16x8 v;
#pragma unroll
    for (int j = 0; j < 8; ++j) v[j] = (__bf16)src[j];
    XG[q * 10000 + row] = v;
}

// ---------------- K0b: build WG (bf16 W in MFMA-B chunk layout) ----------------
__global__ __launch_bounds__(256) void k_build_wg(const float* __restrict__ W,
                                                  bf16x8* __restrict__ WG) {
    int e = blockIdx.x * 256 + threadIdx.x;     // 0..8191
    int q = e >> 8;
    int n = e & 255;
    bf16x8 v;
#pragma unroll
    for (int j = 0; j < 8; ++j) v[j] = (__bf16)W[(q * 8 + j) * 256 + n];
    WG[e] = v;
}

// ---------------- K1: inp = X@W (MFMA), fused tanh/e/hsum (LDS cross-wave reduce) ----------------
__global__ __launch_bounds__(256) void k_gemm1(const bf16x8* __restrict__ XG,
                                               const bf16x8* __restrict__ WG,
                                               const float* __restrict__ bvec,
                                               const float* __restrict__ avec,
                                               float* __restrict__ inp,
                                               float* __restrict__ evec,
                                               float* __restrict__ hsumv) {
    __shared__ bf16x8 Ash[320];    // (g*80 + r)
    __shared__ bf16x8 Bsh[1024];   // (g*256 + n)
    __shared__ float ePart[4][80];
    __shared__ float hPart[4][80];
    int tid = threadIdx.x, wid = tid >> 6, lane = tid & 63;
    int l15 = lane & 15, l4 = lane >> 4;
    int mb = blockIdx.x;

    f32x4 acc[4][5];
#pragma unroll
    for (int c = 0; c < 4; ++c)
#pragma unroll
        for (int rt = 0; rt < 5; ++rt) acc[c][rt] = f32x4{0.f, 0.f, 0.f, 0.f};

    for (int kb = 0; kb < 8; ++kb) {
        for (int rr = wid; rr < 5; rr += 4) {
            int c = rr * 64 + lane;
            int g = c / 80, r = c - g * 80;
            gl_lds16(XG + ((kb * 4 + g) * 10000 + mb * 80 + r), (char*)Ash + rr * 1024);
        }
        for (int rr = wid; rr < 16; rr += 4)
            gl_lds16(WG + kb * 1024 + rr * 64 + lane, (char*)Bsh + rr * 1024);
        __syncthreads();

        bf16x8 af[5];
#pragma unroll
        for (int rt = 0; rt < 5; ++rt) af[rt] = Ash[l4 * 80 + rt * 16 + l15];
#pragma unroll
        for (int c = 0; c < 4; ++c) {
            bf16x8 bf = Bsh[l4 * 256 + (wid * 4 + c) * 16 + l15];
#pragma unroll
            for (int rt = 0; rt < 5; ++rt)
                acc[c][rt] = __builtin_amdgcn_mfma_f32_16x16x32_bf16(af[rt], bf, acc[c][rt], 0, 0, 0);
        }
        __syncthreads();
    }

    float pe[5][4], ph[5][4];
#pragma unroll
    for (int rt = 0; rt < 5; ++rt)
#pragma unroll
        for (int rg = 0; rg < 4; ++rg) { pe[rt][rg] = 0.f; ph[rt][rg] = 0.f; }

#pragma unroll
    for (int c = 0; c < 4; ++c) {
        int col = (wid * 4 + c) * 16 + l15;
        float av = avec[col];
        float bv = bvec[col];
#pragma unroll
        for (int rt = 0; rt < 5; ++rt) {
#pragma unroll
            for (int rg = 0; rg < 4; ++rg) {
                int row = mb * 80 + rt * 16 + l4 * 4 + rg;
                float v = acc[c][rt][rg];            // inp excludes bias (per reference)
                inp[row * 256 + col] = v;
                float h = tanhf(v + bv);
                pe[rt][rg] += h * av;
                ph[rt][rg] += h;
            }
        }
    }
#pragma unroll
    for (int rt = 0; rt < 5; ++rt) {
#pragma unroll
        for (int rg = 0; rg < 4; ++rg) {
            float se = pe[rt][rg], sh = ph[rt][rg];
#pragma unroll
            for (int m = 1; m < 16; m <<= 1) {
                se += __shfl_xor(se, m);
                sh += __shfl_xor(sh, m);
            }
            if (l15 == 0) {
                int lr = rt * 16 + l4 * 4 + rg;   // 0..79
                ePart[wid][lr] = se;
                hPart[wid][lr] = sh;
            }
        }
    }
    __syncthreads();
    if (tid < 80) {
        float e = ePart[0][tid] + ePart[1][tid] + ePart[2][tid] + ePart[3][tid];
        float h = hPart[0][tid] + hPart[1][tid] + hPart[2][tid] + hPart[3][tid];
        evec[mb * 80 + tid] = e;
        hsumv[mb * 80 + tid] = h;
    }
}

// ---------------- K2: global max of e over valid nodes, then g = exp(e-gmax) ----------------
__global__ __launch_bounds__(1024) void k_softmax_g(const float* __restrict__ evec,
                                                    const float* __restrict__ hsumv,
                                                    float* __restrict__ gv) {
    __shared__ float red[1024];
    int tid = threadIdx.x;
    float m = -3.0e38f;
    for (int i = tid; i < NN; i += 1024)
        if (hsumv[i] != 0.0f) m = fmaxf(m, evec[i]);
    red[tid] = m;
    __syncthreads();
    for (int s = 512; s > 0; s >>= 1) {
        if (tid < s) red[tid] = fmaxf(red[tid], red[tid + s]);
        __syncthreads();
    }
    float gmax = red[0];
    if (gmax < -1.0e37f) gmax = 0.0f;
    for (int i = tid; i < 10016; i += 1024) {
        float g = 0.0f;
        if (i < NN && hsumv[i] != 0.0f) g = expf(evec[i] - gmax);
        gv[i] = g;
    }
}

// ---------------- K3: build YG = pre-chunked bf16 B tiles for the big GEMM ----------------
// grid 318: kb >= 313 hits the k<NN guard everywhere -> zero pads
__global__ __launch_bounds__(256) void k_build_yg(const float* __restrict__ inp,
                                                  const float* __restrict__ gv,
                                                  bf16x8* __restrict__ YG) {
    int kb = blockIdx.x;   // 0..317
    for (int c = threadIdx.x; c < 1088; c += 256) {
        int gq = c / 272, n = c - gq * 272;
        int k0 = kb * 32 + gq * 8;
        bf16x8 v;
#pragma unroll
        for (int j = 0; j < 8; ++j) {
            int k = k0 + j;
            float val = 0.0f;
            if (k < NN) {
                float gk = gv[k];
                if (n < 256) val = gk * inp[k * 256 + n];
                else if (n == 256) val = gk;
            }
            v[j] = (__bf16)val;
        }
        YG[kb * 1088 + c] = v;
    }
}

// ---- int32 {0,1} pair-of-int4 -> bf16x8 {0,1} fragment ----
__device__ __forceinline__ bf16x8 cvt_adj(int4 a, int4 b) {
    union { bf16x8 v; unsigned int u[4]; } r;
    r.u[0] = (a.x > 0 ? 0x3F80u : 0u) | (a.y > 0 ? 0x3F800000u : 0u);
    r.u[1] = (a.z > 0 ? 0x3F80u : 0u) | (a.w > 0 ? 0x3F800000u : 0u);
    r.u[2] = (b.x > 0 ? 0x3F80u : 0u) | (b.y > 0 ? 0x3F800000u : 0u);
    r.u[3] = (b.z > 0 ? 0x3F80u : 0u) | (b.w > 0 ? 0x3F800000u : 0u);
    return r.v;
}

// ---------------- K4: num_kc = adj @ Y  (R3 skeleton + A-prefetch depth 2) ----------------
// BM=128: 4 waves x 32 rows (2 row-tiles); all 17 col-tiles per wave; 68 MFMA/wave/step.
// B: LDS double-buffer, staged 1 ahead via gl_lds (9/8 per wave). A: TWO register
// sets aA/aB, each reloaded in place 2 steps ahead (loadA(s+2) right after cvt) —
// A-loads get >=1.5 steps of flight time instead of <1. End-of-step vmcnt(8):
// outstanding = A(s+1)[8] + own gl_lds[9/8] + A(s+2)[8]; drains gl_lds (+A(s+1),
// already ~1.5 steps old), keeps A(s+2) in flight. Never drains to 0.
__global__ __launch_bounds__(256, 2) void k_attn_gemm(const int* __restrict__ adj,
                                                      const bf16x8* __restrict__ YG,
                                                      float* __restrict__ pnum) {
    __shared__ bf16x8 Bsh[2][2176];   // double-buffered 64x272 bf16 tiles (69632 B)
    int tid = threadIdx.x, wid = tid >> 6, lane = tid & 63;
    int l15 = lane & 15, l4 = lane >> 4;
    int bid = blockIdx.x;
    int mb = bid / KSPLIT, kc = bid % KSPLIT;   // R3 mapping (kc fast); L3 catches cross-XCD adj reuse
    int s0 = (kc * KSTEP64) / KSPLIT, s1 = ((kc + 1) * KSTEP64) / KSPLIT;

    // A addressing: row = l15 (+16 for tile1), k-group = l4*8 (verified A-frag layout)
    int mrow = mb * 128 + wid * 32 + l15;
    const int* pA = adj + (size_t)min(mrow, NN - 1) * 10000;
    const int* pB = adj + (size_t)min(mrow + 16, NN - 1) * 10000;
    int kgrp = l4 * 8;

    f32x4 acc[2][17];
#pragma unroll
    for (int t = 0; t < 2; ++t)
#pragma unroll
        for (int ct = 0; ct < 17; ++ct) acc[t][ct] = f32x4{0.f, 0.f, 0.f, 0.f};

    int4 aA[8], aB[8];

    auto stageB = [&](int sTile, int bufIdx) {
        const bf16x8* src = YG + (size_t)sTile * 2176;
        char* dst = (char*)&Bsh[bufIdx][0];
#pragma unroll
        for (int i = 0; i < 9; ++i) {
            int rr = wid + i * 4;
            if (rr < 34) gl_lds16(src + rr * 64 + lane, dst + rr * 1024);   // wid0/1: 9, wid2/3: 8
        }
    };
    auto loadA = [&](int sTile, int4* dstA) {
        int kk0 = min(sTile * 64 + kgrp, 9992);        // clamp safe: B is 0 for k>=NN
        int kk1 = min(sTile * 64 + 32 + kgrp, 9992);
        const int4* qa0 = (const int4*)(pA + kk0);
        const int4* qb0 = (const int4*)(pB + kk0);
        const int4* qa1 = (const int4*)(pA + kk1);
        const int4* qb1 = (const int4*)(pB + kk1);
        dstA[0] = qa0[0]; dstA[1] = qa0[1]; dstA[2] = qb0[0]; dstA[3] = qb0[1];
        dstA[4] = qa1[0]; dstA[5] = qa1[1]; dstA[6] = qb1[0]; dstA[7] = qb1[1];
    };
    auto compute = [&](bf16x8 f00, bf16x8 f01, bf16x8 f10, bf16x8 f11, int bufIdx) {
#pragma unroll
        for (int ct = 0; ct < 17; ++ct) {
            bf16x8 fb0 = Bsh[bufIdx][l4 * 272 + ct * 16 + l15];
            acc[0][ct] = __builtin_amdgcn_mfma_f32_16x16x32_bf16(f00, fb0, acc[0][ct], 0, 0, 0);
            acc[1][ct] = __builtin_amdgcn_mfma_f32_16x16x32_bf16(f01, fb0, acc[1][ct], 0, 0, 0);
            bf16x8 fb1 = Bsh[bufIdx][1088 + l4 * 272 + ct * 16 + l15];
            acc[0][ct] = __builtin_amdgcn_mfma_f32_16x16x32_bf16(f10, fb1, acc[0][ct], 0, 0, 0);
            acc[1][ct] = __builtin_amdgcn_mfma_f32_16x16x32_bf16(f11, fb1, acc[1][ct], 0, 0, 0);
        }
    };

    // ---- prologue: stage B(s0); issue A(s0) and A(s0+1) ----
    stageB(s0, 0);
    __builtin_amdgcn_sched_barrier(0);
    loadA(s0, aA);
    loadA(s0 + 1, aB);
    asm volatile("s_waitcnt vmcnt(16)" ::: "memory");   // drain own gl_lds; keep both A sets
    __builtin_amdgcn_s_barrier();

    // ---- main loop, 2-unrolled: body(s) uses setX, reloads setX with A(s+2) ----
    int s = s0, buf = 0;
#define K4_BODY(ASET)                                                          \
    {                                                                          \
        stageB(s + 1, buf ^ 1);                                                \
        __builtin_amdgcn_sched_barrier(0);                                     \
        bf16x8 f00 = cvt_adj(ASET[0], ASET[1]);                                \
        bf16x8 f01 = cvt_adj(ASET[2], ASET[3]);                                \
        bf16x8 f10 = cvt_adj(ASET[4], ASET[5]);                                \
        bf16x8 f11 = cvt_adj(ASET[6], ASET[7]);                                \
        loadA(s + 2, ASET);                                                    \
        __builtin_amdgcn_sched_barrier(0);                                     \
        compute(f00, f01, f10, f11, buf);                                      \
        asm volatile("s_waitcnt vmcnt(8)" ::: "memory");                       \
        __builtin_amdgcn_s_barrier();                                          \
        buf ^= 1; ++s;                                                         \
    }
    while (s + 2 <= s1) {
        K4_BODY(aA)
        K4_BODY(aB)
    }
#undef K4_BODY
    if (s < s1) {   // odd tail: B(s) staged+barrier'd; A(s) in aA (loaded 2 bodies ago)
        bf16x8 f00 = cvt_adj(aA[0], aA[1]);
        bf16x8 f01 = cvt_adj(aA[2], aA[3]);
        bf16x8 f10 = cvt_adj(aA[4], aA[5]);
        bf16x8 f11 = cvt_adj(aA[6], aA[7]);
        compute(f00, f01, f10, f11, buf);
    }

    // ---- epilogue: plain stores to per-kc partial buffer ----
    float* base = pnum + (size_t)kc * 10000 * 272;
    int r0 = mb * 128 + wid * 32;
#pragma unroll
    for (int t = 0; t < 2; ++t) {
#pragma unroll
        for (int ct = 0; ct < 17; ++ct) {
            int col = ct * 16 + l15;
#pragma unroll
            for (int rg = 0; rg < 4; ++rg) {
                int row = r0 + t * 16 + l4 * 4 + rg;
                if (row < NN) base[(size_t)row * 272 + col] = acc[t][ct][rg];
            }
        }
    }
}

// ---------------- K5: out = (sum_kc num_kc) / max(sum_kc den_kc, 1e-30) ----------------
__global__ __launch_bounds__(256) void k_finalize(const float* __restrict__ pnum,
                                                  float* __restrict__ out) {
    int idx = blockIdx.x * 256 + threadIdx.x;   // 0..639999 (float4 units)
    int i = idx >> 6, q = idx & 63;
    float4 sv = {0.f, 0.f, 0.f, 0.f};
    float den = 0.f;
#pragma unroll
    for (int kc = 0; kc < KSPLIT; ++kc) {
        const float* row = pnum + ((size_t)kc * 10000 + i) * 272;
        float4 v = ((const float4*)row)[q];
        sv.x += v.x; sv.y += v.y; sv.z += v.z; sv.w += v.w;
        den += row[256];
    }
    float r = 1.0f / fmaxf(den, 1e-30f);
    float4 o;
    o.x = sv.x * r; o.y = sv.y * r; o.z = sv.z * r; o.w = sv.w * r;
    ((float4*)(out + (size_t)i * 256))[q] = o;
}

extern "C" void kernel_launch(void* const* d_in, const int* in_sizes, int n_in,
                              void* d_out, int out_size, void* d_ws, size_t ws_size,
                              hipStream_t stream) {
    const float* X    = (const float*)d_in[0];
    const int*   adj  = (const int*)d_in[1];
    const float* W    = (const float*)d_in[3];
    const float* bvec = (const float*)d_in[4];
    const float* avec = (const float*)d_in[5];
    float* out = (float*)d_out;

    char* ws = (char*)d_ws;
    bf16x8* XG   = (bf16x8*)(ws + XG_OFF);
    bf16x8* WG   = (bf16x8*)(ws + WG_OFF);
    float*  inp  = (float*)(ws + INP_OFF);
    float*  evec = (float*)(ws + E_OFF);
    float*  hsv  = (float*)(ws + HS_OFF);
    float*  gv   = (float*)(ws + G_OFF);
    bf16x8* YG   = (bf16x8*)(ws + YG_OFF);
    float*  pnum = (float*)(ws + PN_OFF);

    k_build_xg<<<1250, 256, 0, stream>>>(X, XG);
    k_build_wg<<<32, 256, 0, stream>>>(W, WG);
    k_gemm1<<<125, 256, 0, stream>>>(XG, WG, bvec, avec, inp, evec, hsv);
    k_softmax_g<<<1, 1024, 0, stream>>>(evec, hsv, gv);
    k_build_yg<<<318, 256, 0, stream>>>(inp, gv, YG);
    k_attn_gemm<<<MB2 * KSPLIT, 256, 0, stream>>>(adj, YG, pnum);
    k_finalize<<<2500, 256, 0, stream>>>(pnum, out);
}